// Round 11
// baseline (328.032 us; speedup 1.0000x reference)
//
#include <hip/hip_runtime.h>
#include <hip/hip_bf16.h>

#define BB 4
#define NN 50000
#define EE 160000
#define KK 1000
#define CH 128
#define TM 64
#define NTILES ((NN + TM - 1) / TM)   // 782
#define SCAN_CHUNK 2048
#define SCAN_NB ((NN + SCAN_CHUNK - 1) / SCAN_CHUNK)  // 25

typedef unsigned short u16;
typedef unsigned int u32;
typedef __attribute__((ext_vector_type(8))) short short8;
typedef __attribute__((ext_vector_type(4))) float f32x4;

// bf16 XOR swizzle for [rows][128] u16 tiles (conflict-free ds_read_b128)
__device__ __forceinline__ int ZIDX(int m, int k) {
  return (m << 7) | (k ^ ((m & 7) << 3));
}

__device__ __forceinline__ u16 f2b(float f) {
  __hip_bfloat16 h = __float2bfloat16(f);   // RNE
  return *reinterpret_cast<u16*>(&h);
}
__device__ __forceinline__ float b2f(u32 lo16) {
  return __uint_as_float(lo16 << 16);
}

// ---------------------------------------------------------------------------
// CSR build (entry packed: (src<<6) | (dst&63))
// ---------------------------------------------------------------------------
__global__ __launch_bounds__(256)
void csr_count(const int* __restrict__ edges, int* __restrict__ cnt) {
  int stride = gridDim.x * blockDim.x;
  for (int i = blockIdx.x * blockDim.x + threadIdx.x; i < BB * EE; i += stride) {
    int b = i / EE, e = i - b * EE;
    int dst = edges[(b * 2 + 1) * EE + e];
    atomicAdd(&cnt[b * NN + dst], 1);
  }
}

__global__ __launch_bounds__(256)
void scan_local(const int* __restrict__ cnt, int* __restrict__ offs,
                int* __restrict__ bsum) {
  __shared__ int sdata[256];
  const int g = blockIdx.y, blk = blockIdx.x, t = threadIdx.x;
  const int i0 = blk * SCAN_CHUNK + t * 8;
  int v[8];
  int s = 0;
#pragma unroll
  for (int j = 0; j < 8; ++j) {
    int i = i0 + j;
    v[j] = (i < NN) ? cnt[g * NN + i] : 0;
    s += v[j];
  }
  sdata[t] = s;
  __syncthreads();
#pragma unroll
  for (int off = 1; off < 256; off <<= 1) {
    int vv = (t >= off) ? sdata[t - off] : 0;
    __syncthreads();
    sdata[t] += vv;
    __syncthreads();
  }
  int run = sdata[t] - s;
#pragma unroll
  for (int j = 0; j < 8; ++j) {
    int i = i0 + j;
    if (i < NN) offs[g * (NN + 1) + i] = run;
    run += v[j];
  }
  if (t == 255) bsum[g * SCAN_NB + blk] = sdata[255];
}

__global__ __launch_bounds__(256)
void scan_add(int* __restrict__ offs, int* __restrict__ woff,
              const int* __restrict__ bsum) {
  const int g = blockIdx.y, blk = blockIdx.x, t = threadIdx.x;
  int boff = 0;
  for (int j = 0; j < blk; ++j) boff += bsum[g * SCAN_NB + j];
  const int i0 = blk * SCAN_CHUNK + t * 8;
#pragma unroll
  for (int j = 0; j < 8; ++j) {
    int i = i0 + j;
    if (i < NN) {
      int val = offs[g * (NN + 1) + i] + boff;
      offs[g * (NN + 1) + i] = val;
      woff[g * NN + i] = val;
    }
  }
  if (blk == SCAN_NB - 1 && t == 255)
    offs[g * (NN + 1) + NN] = boff + bsum[g * SCAN_NB + blk];
}

__global__ __launch_bounds__(256)
void csr_fill(const int* __restrict__ edges, int* __restrict__ woff,
              int* __restrict__ csr) {
  int stride = gridDim.x * blockDim.x;
  for (int i = blockIdx.x * blockDim.x + threadIdx.x; i < BB * EE; i += stride) {
    int b = i / EE, e = i - b * EE;
    int src = edges[(b * 2) * EE + e];
    int dst = edges[(b * 2 + 1) * EE + e];
    int pos = atomicAdd(&woff[b * NN + dst], 1);
    csr[b * EE + pos] = (src << 6) | (dst & 63);
  }
}

// ---------------------------------------------------------------------------
// Weight prep: bf16 fragment-ordered images for coalesced per-wave loads.
// Flat index f = ((((mat*4+wv)*2+ct)*4+ks)*64+lane)*8+e
//   n = wv*32 + ct*16 + (lane&15); k = ks*32 + (lane>>4)*8 + e;  img[f]=w[k][n]
// mats: 0:w2[0]  1:w1r[0]  2:w2[1]  3:w1r[1]  4:w2[2]
// ---------------------------------------------------------------------------
__global__ __launch_bounds__(256)
void prep_weights(const float* __restrict__ w1r, const float* __restrict__ w2,
                  u16* __restrict__ img) {
  int f = blockIdx.x * blockDim.x + threadIdx.x;
  if (f >= 5 * CH * CH) return;
  int e = f & 7;
  int lane = (f >> 3) & 63;
  int ks = (f >> 9) & 3;
  int ct = (f >> 11) & 1;
  int wv = (f >> 12) & 3;
  int mat = f >> 14;
  int n = wv * 32 + ct * 16 + (lane & 15);
  int k = ks * 32 + (lane >> 4) * 8 + e;
  const float* src;
  switch (mat) {
    case 0: src = w2; break;
    case 1: src = w1r; break;
    case 2: src = w2 + 16384; break;
    case 3: src = w1r + 16384; break;
    default: src = w2 + 32768; break;
  }
  img[f] = f2b(src[(k << 7) + n]);
}

// ---------------------------------------------------------------------------
// Fused GIN layer — R7 structure; occupancy target raised to 8 blocks/CU
// (VGPR 48 <= 64 cap, LDS 17.4KB x 8 = 139KB <= 160KB -> 32 waves/CU).
// 256 thr (4 waves), tile 64 nodes x 128 ch; 4 lanes/node x 32ch register acc.
// Weights: per-wave coalesced register fragments from img (L2).
// ---------------------------------------------------------------------------
template <bool L0>
__global__ __launch_bounds__(256, 8)
void gin_layer(const void* __restrict__ hin_v, u16* __restrict__ hout,
               const int* __restrict__ offs, const int* __restrict__ csr,
               const float* __restrict__ w1f,       // L0 only (128)
               const u16* __restrict__ imgf_w1,     // !L0 fragment image
               const u16* __restrict__ imgf_w2,
               const float* __restrict__ b1v, const float* __restrict__ b2v) {
  __shared__ u16 zt[TM * CH];        // 16KB
  __shared__ float part[TM * 4];     // 1KB (L0 reduction only)

  const int tid = threadIdx.x;
  const int lane = tid & 63;
  const int wv = tid >> 6;
  const int lr = lane & 15;
  const int g = lane >> 4;
  const int cb = wv * 32;

  const int b = blockIdx.x / NTILES;
  const int t0 = (blockIdx.x % NTILES) * TM;
  const int nm = min(TM, NN - t0);

  const int m = tid >> 2;
  const int p = tid & 3;

  if (L0) {
    // ---- per-node scalar gather (no atomics) ----
    const float* x = (const float*)hin_v;
    int start = 0, end = 0;
    if (m < nm) {
      start = offs[b * (NN + 1) + t0 + m];
      end = offs[b * (NN + 1) + t0 + m + 1];
    }
    float s = 0.f;
    if (m < nm) {
      if (p == 0) s = x[b * NN + t0 + m];
      for (int e = start + p; e < end; e += 4)
        s += x[b * NN + (((u32)csr[b * EE + e]) >> 6)];
    }
    part[(m << 2) + p] = s;
    __syncthreads();
    float z0 = part[m << 2] + part[(m << 2) + 1] + part[(m << 2) + 2] +
               part[(m << 2) + 3];
#pragma unroll
    for (int jj = 0; jj < 4; ++jj) {
      int c0 = (p << 5) + (jj << 3);
      short8 tv;
#pragma unroll
      for (int t = 0; t < 8; ++t)
        tv[t] = (short)f2b(fmaxf(z0 * w1f[c0 + t] + b1v[c0 + t], 0.f));
      *(short8*)&zt[ZIDX(m, c0)] = tv;
    }
    __syncthreads();
  } else {
    const u16* h = (const u16*)hin_v;
    int start = 0, end = 0;
    if (m < nm) {
      start = offs[b * (NN + 1) + t0 + m];
      end = offs[b * (NN + 1) + t0 + m + 1];
    }
    float acc[32];
    if (m < nm) {
      const uint4* hr =
          (const uint4*)(h + ((size_t)(b * NN + t0 + m) << 7)) + (p << 2);
#pragma unroll
      for (int j = 0; j < 4; ++j) {
        uint4 v = hr[j];
        acc[j*8+0] = b2f(v.x & 0xffff); acc[j*8+1] = b2f(v.x >> 16);
        acc[j*8+2] = b2f(v.y & 0xffff); acc[j*8+3] = b2f(v.y >> 16);
        acc[j*8+4] = b2f(v.z & 0xffff); acc[j*8+5] = b2f(v.z >> 16);
        acc[j*8+6] = b2f(v.w & 0xffff); acc[j*8+7] = b2f(v.w >> 16);
      }
      for (int e = start; e < end; ++e) {
        int src = ((u32)csr[b * EE + e]) >> 6;
        const uint4* sr =
            (const uint4*)(h + ((size_t)(b * NN + src) << 7)) + (p << 2);
#pragma unroll
        for (int j = 0; j < 4; ++j) {
          uint4 v = sr[j];
          acc[j*8+0] += b2f(v.x & 0xffff); acc[j*8+1] += b2f(v.x >> 16);
          acc[j*8+2] += b2f(v.y & 0xffff); acc[j*8+3] += b2f(v.y >> 16);
          acc[j*8+4] += b2f(v.z & 0xffff); acc[j*8+5] += b2f(v.z >> 16);
          acc[j*8+6] += b2f(v.w & 0xffff); acc[j*8+7] += b2f(v.w >> 16);
        }
      }
    } else {
#pragma unroll
      for (int t = 0; t < 32; ++t) acc[t] = 0.f;
    }
#pragma unroll
    for (int jj = 0; jj < 4; ++jj) {
      int c0 = (p << 5) + (jj << 3);
      short8 tv;
#pragma unroll
      for (int t = 0; t < 8; ++t) tv[t] = (short)f2b(acc[(jj << 3) + t]);
      *(short8*)&zt[ZIDX(m, c0)] = tv;
    }
    __syncthreads();

    // ---- GEMM1: t = relu(z @ w1 + b1) ----
    short8 fw1[2][4];
#pragma unroll
    for (int ct = 0; ct < 2; ++ct)
#pragma unroll
      for (int ks = 0; ks < 4; ++ks)
        fw1[ct][ks] = *(const short8*)
            &imgf_w1[(((((wv << 1) | ct) << 2) | ks) << 9) + (lane << 3)];
    f32x4 a1[4][2];
#pragma unroll
    for (int rt = 0; rt < 4; ++rt)
#pragma unroll
      for (int ct = 0; ct < 2; ++ct) a1[rt][ct] = (f32x4){0.f, 0.f, 0.f, 0.f};
#pragma unroll
    for (int ks = 0; ks < 4; ++ks) {
      int kb = (ks << 5) + (g << 3);
      short8 af[4];
#pragma unroll
      for (int rt = 0; rt < 4; ++rt)
        af[rt] = *(const short8*)&zt[ZIDX((rt << 4) + lr, kb)];
#pragma unroll
      for (int rt = 0; rt < 4; ++rt)
#pragma unroll
        for (int ct = 0; ct < 2; ++ct)
          a1[rt][ct] = __builtin_amdgcn_mfma_f32_16x16x32_bf16(
              af[rt], fw1[ct][ks], a1[rt][ct], 0, 0, 0);
    }
    __syncthreads();   // all zt reads done before overwrite

    // ---- t -> zt (bf16 swizzled) ----
#pragma unroll
    for (int rt = 0; rt < 4; ++rt)
#pragma unroll
      for (int ct = 0; ct < 2; ++ct) {
        int col = cb + (ct << 4) + lr;
        float bias = b1v[col];
#pragma unroll
        for (int r = 0; r < 4; ++r) {
          int row = (rt << 4) + (g << 2) + r;
          zt[ZIDX(row, col)] = f2b(fmaxf(a1[rt][ct][r] + bias, 0.f));
        }
      }
    __syncthreads();
  }

  // ---- GEMM2: o = relu(t @ w2 + b2) ----
  short8 fw2[2][4];
#pragma unroll
  for (int ct = 0; ct < 2; ++ct)
#pragma unroll
    for (int ks = 0; ks < 4; ++ks)
      fw2[ct][ks] = *(const short8*)
          &imgf_w2[(((((wv << 1) | ct) << 2) | ks) << 9) + (lane << 3)];
  f32x4 a2[4][2];
#pragma unroll
  for (int rt = 0; rt < 4; ++rt)
#pragma unroll
    for (int ct = 0; ct < 2; ++ct) a2[rt][ct] = (f32x4){0.f, 0.f, 0.f, 0.f};
#pragma unroll
  for (int ks = 0; ks < 4; ++ks) {
    int kb = (ks << 5) + (g << 3);
    short8 af[4];
#pragma unroll
    for (int rt = 0; rt < 4; ++rt)
      af[rt] = *(const short8*)&zt[ZIDX((rt << 4) + lr, kb)];
#pragma unroll
    for (int rt = 0; rt < 4; ++rt)
#pragma unroll
      for (int ct = 0; ct < 2; ++ct)
        a2[rt][ct] = __builtin_amdgcn_mfma_f32_16x16x32_bf16(
            af[rt], fw2[ct][ks], a2[rt][ct], 0, 0, 0);
  }
  __syncthreads();   // all zt reads done before overwrite

  // ---- o -> zt (reuse), then coalesced copy-out ----
#pragma unroll
  for (int rt = 0; rt < 4; ++rt)
#pragma unroll
    for (int ct = 0; ct < 2; ++ct) {
      int col = cb + (ct << 4) + lr;
      float bias = b2v[col];
#pragma unroll
      for (int r = 0; r < 4; ++r) {
        int row = (rt << 4) + (g << 2) + r;
        zt[ZIDX(row, col)] = f2b(fmaxf(a2[rt][ct][r] + bias, 0.f));
      }
    }
  __syncthreads();

  for (int i = tid; i < 1024; i += 256) {
    int mm = i >> 4, c0 = (i & 15) << 3;
    if (mm < nm) {
      uint4 v = *(const uint4*)&zt[ZIDX(mm, c0)];
      *(uint4*)&hout[(((size_t)(b * NN + t0 + mm)) << 7) + c0] = v;
    }
  }
}

// ---------------------------------------------------------------------------
// Heads (emb is bf16)
// ---------------------------------------------------------------------------
__global__ __launch_bounds__(256)
void heads_kernel(const u16* __restrict__ emb, const int* __restrict__ didx,
                  const int* __restrict__ nopp, const float* __restrict__ pol_w,
                  const float* __restrict__ pol_b, const float* __restrict__ val_w,
                  const float* __restrict__ val_b, float* __restrict__ out) {
  int gw = (blockIdx.x * blockDim.x + threadIdx.x) >> 6;
  int lane = threadIdx.x & 63;
  if (gw >= BB * KK) return;
  int b = gw / KK, k = gw - b * KK;
  int node = didx[b * KK + k];
  const u16* e = emb + (((size_t)(b * NN + node)) << 7);
  u32 v = *(const u32*)&e[lane << 1];
  float f0 = __uint_as_float(v << 16);
  float f1 = __uint_as_float(v & 0xffff0000u);
  float s = f0 * pol_w[lane << 1] + f1 * pol_w[(lane << 1) + 1];
#pragma unroll
  for (int off = 32; off; off >>= 1) s += __shfl_down(s, off);
  if (lane == 0) out[b * KK + k] = s + pol_b[0];
  if (k == nopp[0]) {
    float vv = f0 * val_w[lane << 1] + f1 * val_w[(lane << 1) + 1];
#pragma unroll
    for (int off = 32; off; off >>= 1) vv += __shfl_down(vv, off);
    if (lane == 0) out[BB * KK + b] = vv + val_b[0];
  }
}

// ---------------------------------------------------------------------------
extern "C" void kernel_launch(void* const* d_in, const int* in_sizes, int n_in,
                              void* d_out, int out_size, void* d_ws, size_t ws_size,
                              hipStream_t stream) {
  const float* x     = (const float*)d_in[0];
  const int*   edges = (const int*)d_in[1];
  const int*   didx  = (const int*)d_in[2];
  const int*   nopp  = (const int*)d_in[3];
  const float* w1f   = (const float*)d_in[4];
  const float* w1r   = (const float*)d_in[5];
  const float* w2    = (const float*)d_in[6];
  const float* b1    = (const float*)d_in[7];
  const float* b2    = (const float*)d_in[8];
  const float* pol_w = (const float*)d_in[9];
  const float* pol_b = (const float*)d_in[10];
  const float* val_w = (const float*)d_in[11];
  const float* val_b = (const float*)d_in[12];
  float* out = (float*)d_out;

  char* ws = (char*)d_ws;
  u16* hA = (u16*)ws;            ws += (size_t)BB * NN * CH * 2;   // 51.2 MB
  u16* hB = (u16*)ws;            ws += (size_t)BB * NN * CH * 2;   // 51.2 MB
  u16* img = (u16*)ws;           ws += (size_t)5 * CH * CH * 2;    // 160 KB
  int* offs = (int*)ws;          ws += (size_t)BB * (NN + 1) * 4;
  int* woff = (int*)ws;          ws += (size_t)BB * NN * 4;
  int* cnt  = (int*)ws;          ws += (size_t)BB * NN * 4;
  int* bsum = (int*)ws;          ws += (size_t)BB * SCAN_NB * 4;
  int* csr  = (int*)ws;          ws += (size_t)BB * EE * 4;

  hipMemsetAsync(cnt, 0, (size_t)BB * NN * 4, stream);
  prep_weights<<<(5 * CH * CH + 255) / 256, 256, 0, stream>>>(w1r, w2, img);
  csr_count<<<1250, 256, 0, stream>>>(edges, cnt);
  scan_local<<<dim3(SCAN_NB, BB), 256, 0, stream>>>(cnt, offs, bsum);
  scan_add<<<dim3(SCAN_NB, BB), 256, 0, stream>>>(offs, woff, bsum);
  csr_fill<<<1250, 256, 0, stream>>>(edges, woff, csr);

  const int tiles = BB * NTILES;
  gin_layer<true><<<tiles, 256, 0, stream>>>(
      x, hA, offs, csr, w1f, nullptr, img, b1, b2);
  gin_layer<false><<<tiles, 256, 0, stream>>>(
      hA, hB, offs, csr, nullptr, img + 1 * 16384, img + 2 * 16384,
      b1 + CH, b2 + CH);
  gin_layer<false><<<tiles, 256, 0, stream>>>(
      hB, hA, offs, csr, nullptr, img + 3 * 16384, img + 4 * 16384,
      b1 + 2 * CH, b2 + 2 * CH);

  heads_kernel<<<(BB * KK * 64 + 255) / 256, 256, 0, stream>>>(
      hA, didx, nopp, pol_w, pol_b, val_w, val_b, out);
}

// Round 12
// 290.242 us; speedup vs baseline: 1.1302x; 1.1302x over previous
//
#include <hip/hip_runtime.h>
#include <hip/hip_bf16.h>

#define BB 4
#define NN 50000
#define EE 160000
#define KK 1000
#define CH 128
#define TM 64
#define NTILES ((NN + TM - 1) / TM)   // 782
#define TILES_TOTAL (BB * NTILES)     // 3128 (divisible by 8)
#define SCAN_CHUNK 2048
#define SCAN_NB ((NN + SCAN_CHUNK - 1) / SCAN_CHUNK)  // 25

typedef unsigned short u16;
typedef unsigned int u32;
typedef __attribute__((ext_vector_type(8))) short short8;
typedef __attribute__((ext_vector_type(4))) float f32x4;

// bf16 XOR swizzle for [rows][128] u16 tiles (conflict-free ds_read_b128)
__device__ __forceinline__ int ZIDX(int m, int k) {
  return (m << 7) | (k ^ ((m & 7) << 3));
}

__device__ __forceinline__ u16 f2b(float f) {
  __hip_bfloat16 h = __float2bfloat16(f);   // RNE
  return *reinterpret_cast<u16*>(&h);
}
__device__ __forceinline__ float b2f(u32 lo16) {
  return __uint_as_float(lo16 << 16);
}

// ---------------------------------------------------------------------------
// prep_all: zero cnt AND build fragment-ordered bf16 weight images (1 kernel).
// img flat index f = ((((mat*4+wv)*2+ct)*4+ks)*64+lane)*8+e
//   n = wv*32 + ct*16 + (lane&15); k = ks*32 + (lane>>4)*8 + e;  img[f]=w[k][n]
// mats: 0:w2[0]  1:w1r[0]  2:w2[1]  3:w1r[1]  4:w2[2]
// ---------------------------------------------------------------------------
__global__ __launch_bounds__(256)
void prep_all(const float* __restrict__ w1r, const float* __restrict__ w2,
              u16* __restrict__ img, int* __restrict__ cnt) {
  int stride = gridDim.x * blockDim.x;
  int gtid = blockIdx.x * blockDim.x + threadIdx.x;
  for (int i = gtid; i < BB * NN; i += stride) cnt[i] = 0;
  for (int f = gtid; f < 5 * CH * CH; f += stride) {
    int e = f & 7;
    int lane = (f >> 3) & 63;
    int ks = (f >> 9) & 3;
    int ct = (f >> 11) & 1;
    int wv = (f >> 12) & 3;
    int mat = f >> 14;
    int n = wv * 32 + ct * 16 + (lane & 15);
    int k = ks * 32 + (lane >> 4) * 8 + e;
    const float* src;
    switch (mat) {
      case 0: src = w2; break;
      case 1: src = w1r; break;
      case 2: src = w2 + 16384; break;
      case 3: src = w1r + 16384; break;
      default: src = w2 + 32768; break;
    }
    img[f] = f2b(src[(k << 7) + n]);
  }
}

// ---------------------------------------------------------------------------
// CSR build (entry packed: (src<<6) | (dst&63))
// ---------------------------------------------------------------------------
__global__ __launch_bounds__(256)
void csr_count(const int* __restrict__ edges, int* __restrict__ cnt) {
  int stride = gridDim.x * blockDim.x;
  for (int i = blockIdx.x * blockDim.x + threadIdx.x; i < BB * EE; i += stride) {
    int b = i / EE, e = i - b * EE;
    int dst = edges[(b * 2 + 1) * EE + e];
    atomicAdd(&cnt[b * NN + dst], 1);
  }
}

__global__ __launch_bounds__(256)
void scan_local(const int* __restrict__ cnt, int* __restrict__ offs,
                int* __restrict__ bsum) {
  __shared__ int sdata[256];
  const int g = blockIdx.y, blk = blockIdx.x, t = threadIdx.x;
  const int i0 = blk * SCAN_CHUNK + t * 8;
  int v[8];
  int s = 0;
#pragma unroll
  for (int j = 0; j < 8; ++j) {
    int i = i0 + j;
    v[j] = (i < NN) ? cnt[g * NN + i] : 0;
    s += v[j];
  }
  sdata[t] = s;
  __syncthreads();
#pragma unroll
  for (int off = 1; off < 256; off <<= 1) {
    int vv = (t >= off) ? sdata[t - off] : 0;
    __syncthreads();
    sdata[t] += vv;
    __syncthreads();
  }
  int run = sdata[t] - s;
#pragma unroll
  for (int j = 0; j < 8; ++j) {
    int i = i0 + j;
    if (i < NN) offs[g * (NN + 1) + i] = run;
    run += v[j];
  }
  if (t == 255) bsum[g * SCAN_NB + blk] = sdata[255];
}

__global__ __launch_bounds__(256)
void scan_add(int* __restrict__ offs, int* __restrict__ woff,
              const int* __restrict__ bsum) {
  const int g = blockIdx.y, blk = blockIdx.x, t = threadIdx.x;
  int boff = 0;
  for (int j = 0; j < blk; ++j) boff += bsum[g * SCAN_NB + j];
  const int i0 = blk * SCAN_CHUNK + t * 8;
#pragma unroll
  for (int j = 0; j < 8; ++j) {
    int i = i0 + j;
    if (i < NN) {
      int val = offs[g * (NN + 1) + i] + boff;
      offs[g * (NN + 1) + i] = val;
      woff[g * NN + i] = val;
    }
  }
  if (blk == SCAN_NB - 1 && t == 255)
    offs[g * (NN + 1) + NN] = boff + bsum[g * SCAN_NB + blk];
}

__global__ __launch_bounds__(256)
void csr_fill(const int* __restrict__ edges, int* __restrict__ woff,
              int* __restrict__ csr) {
  int stride = gridDim.x * blockDim.x;
  for (int i = blockIdx.x * blockDim.x + threadIdx.x; i < BB * EE; i += stride) {
    int b = i / EE, e = i - b * EE;
    int src = edges[(b * 2) * EE + e];
    int dst = edges[(b * 2 + 1) * EE + e];
    int pos = atomicAdd(&woff[b * NN + dst], 1);
    csr[b * EE + pos] = (src << 6) | (dst & 63);
  }
}

// ---------------------------------------------------------------------------
// Fused GIN layer — R7-proven structure + XCD-aware tile swizzle.
// blockIdx -> tile: (wg&7)*(TILES/8) + (wg>>3) gives each XCD a contiguous
// tile chunk (~half a graph, 12.8MB h working set vs 51.2MB unswizzled) so
// random neighbor reads hit the XCD-private L2 more often.
// 256 thr (4 waves), tile 64 nodes x 128 ch; 4 lanes/node x 32ch register acc.
// Weights: per-wave coalesced register fragments from img (L2). LDS 17KB.
// ---------------------------------------------------------------------------
template <bool L0>
__global__ __launch_bounds__(256, 4)
void gin_layer(const void* __restrict__ hin_v, u16* __restrict__ hout,
               const int* __restrict__ offs, const int* __restrict__ csr,
               const float* __restrict__ w1f,       // L0 only (128)
               const u16* __restrict__ imgf_w1,     // !L0 fragment image
               const u16* __restrict__ imgf_w2,
               const float* __restrict__ b1v, const float* __restrict__ b2v) {
  __shared__ u16 zt[TM * CH];        // 16KB
  __shared__ float part[TM * 4];     // 1KB (L0 reduction only)

  const int tid = threadIdx.x;
  const int lane = tid & 63;
  const int wv = tid >> 6;
  const int lr = lane & 15;
  const int g = lane >> 4;
  const int cb = wv * 32;

  const int wg = blockIdx.x;
  const int tile = (wg & 7) * (TILES_TOTAL / 8) + (wg >> 3);  // XCD swizzle
  const int b = tile / NTILES;
  const int t0 = (tile % NTILES) * TM;
  const int nm = min(TM, NN - t0);

  const int m = tid >> 2;
  const int p = tid & 3;

  if (L0) {
    // ---- per-node scalar gather (no atomics) ----
    const float* x = (const float*)hin_v;
    int start = 0, end = 0;
    if (m < nm) {
      start = offs[b * (NN + 1) + t0 + m];
      end = offs[b * (NN + 1) + t0 + m + 1];
    }
    float s = 0.f;
    if (m < nm) {
      if (p == 0) s = x[b * NN + t0 + m];
      for (int e = start + p; e < end; e += 4)
        s += x[b * NN + (((u32)csr[b * EE + e]) >> 6)];
    }
    part[(m << 2) + p] = s;
    __syncthreads();
    float z0 = part[m << 2] + part[(m << 2) + 1] + part[(m << 2) + 2] +
               part[(m << 2) + 3];
#pragma unroll
    for (int jj = 0; jj < 4; ++jj) {
      int c0 = (p << 5) + (jj << 3);
      short8 tv;
#pragma unroll
      for (int t = 0; t < 8; ++t)
        tv[t] = (short)f2b(fmaxf(z0 * w1f[c0 + t] + b1v[c0 + t], 0.f));
      *(short8*)&zt[ZIDX(m, c0)] = tv;
    }
    __syncthreads();
  } else {
    const u16* h = (const u16*)hin_v;
    int start = 0, end = 0;
    if (m < nm) {
      start = offs[b * (NN + 1) + t0 + m];
      end = offs[b * (NN + 1) + t0 + m + 1];
    }
    float acc[32];
    if (m < nm) {
      const uint4* hr =
          (const uint4*)(h + ((size_t)(b * NN + t0 + m) << 7)) + (p << 2);
#pragma unroll
      for (int j = 0; j < 4; ++j) {
        uint4 v = hr[j];
        acc[j*8+0] = b2f(v.x & 0xffff); acc[j*8+1] = b2f(v.x >> 16);
        acc[j*8+2] = b2f(v.y & 0xffff); acc[j*8+3] = b2f(v.y >> 16);
        acc[j*8+4] = b2f(v.z & 0xffff); acc[j*8+5] = b2f(v.z >> 16);
        acc[j*8+6] = b2f(v.w & 0xffff); acc[j*8+7] = b2f(v.w >> 16);
      }
      for (int e = start; e < end; ++e) {
        int src = ((u32)csr[b * EE + e]) >> 6;
        const uint4* sr =
            (const uint4*)(h + ((size_t)(b * NN + src) << 7)) + (p << 2);
#pragma unroll
        for (int j = 0; j < 4; ++j) {
          uint4 v = sr[j];
          acc[j*8+0] += b2f(v.x & 0xffff); acc[j*8+1] += b2f(v.x >> 16);
          acc[j*8+2] += b2f(v.y & 0xffff); acc[j*8+3] += b2f(v.y >> 16);
          acc[j*8+4] += b2f(v.z & 0xffff); acc[j*8+5] += b2f(v.z >> 16);
          acc[j*8+6] += b2f(v.w & 0xffff); acc[j*8+7] += b2f(v.w >> 16);
        }
      }
    } else {
#pragma unroll
      for (int t = 0; t < 32; ++t) acc[t] = 0.f;
    }
#pragma unroll
    for (int jj = 0; jj < 4; ++jj) {
      int c0 = (p << 5) + (jj << 3);
      short8 tv;
#pragma unroll
      for (int t = 0; t < 8; ++t) tv[t] = (short)f2b(acc[(jj << 3) + t]);
      *(short8*)&zt[ZIDX(m, c0)] = tv;
    }
    __syncthreads();

    // ---- GEMM1: t = relu(z @ w1 + b1) ----
    short8 fw1[2][4];
#pragma unroll
    for (int ct = 0; ct < 2; ++ct)
#pragma unroll
      for (int ks = 0; ks < 4; ++ks)
        fw1[ct][ks] = *(const short8*)
            &imgf_w1[(((((wv << 1) | ct) << 2) | ks) << 9) + (lane << 3)];
    f32x4 a1[4][2];
#pragma unroll
    for (int rt = 0; rt < 4; ++rt)
#pragma unroll
      for (int ct = 0; ct < 2; ++ct) a1[rt][ct] = (f32x4){0.f, 0.f, 0.f, 0.f};
#pragma unroll
    for (int ks = 0; ks < 4; ++ks) {
      int kb = (ks << 5) + (g << 3);
      short8 af[4];
#pragma unroll
      for (int rt = 0; rt < 4; ++rt)
        af[rt] = *(const short8*)&zt[ZIDX((rt << 4) + lr, kb)];
#pragma unroll
      for (int rt = 0; rt < 4; ++rt)
#pragma unroll
        for (int ct = 0; ct < 2; ++ct)
          a1[rt][ct] = __builtin_amdgcn_mfma_f32_16x16x32_bf16(
              af[rt], fw1[ct][ks], a1[rt][ct], 0, 0, 0);
    }
    __syncthreads();   // all zt reads done before overwrite

    // ---- t -> zt (bf16 swizzled) ----
#pragma unroll
    for (int rt = 0; rt < 4; ++rt)
#pragma unroll
      for (int ct = 0; ct < 2; ++ct) {
        int col = cb + (ct << 4) + lr;
        float bias = b1v[col];
#pragma unroll
        for (int r = 0; r < 4; ++r) {
          int row = (rt << 4) + (g << 2) + r;
          zt[ZIDX(row, col)] = f2b(fmaxf(a1[rt][ct][r] + bias, 0.f));
        }
      }
    __syncthreads();
  }

  // ---- GEMM2: o = relu(t @ w2 + b2) ----
  short8 fw2[2][4];
#pragma unroll
  for (int ct = 0; ct < 2; ++ct)
#pragma unroll
    for (int ks = 0; ks < 4; ++ks)
      fw2[ct][ks] = *(const short8*)
          &imgf_w2[(((((wv << 1) | ct) << 2) | ks) << 9) + (lane << 3)];
  f32x4 a2[4][2];
#pragma unroll
  for (int rt = 0; rt < 4; ++rt)
#pragma unroll
    for (int ct = 0; ct < 2; ++ct) a2[rt][ct] = (f32x4){0.f, 0.f, 0.f, 0.f};
#pragma unroll
  for (int ks = 0; ks < 4; ++ks) {
    int kb = (ks << 5) + (g << 3);
    short8 af[4];
#pragma unroll
    for (int rt = 0; rt < 4; ++rt)
      af[rt] = *(const short8*)&zt[ZIDX((rt << 4) + lr, kb)];
#pragma unroll
    for (int rt = 0; rt < 4; ++rt)
#pragma unroll
      for (int ct = 0; ct < 2; ++ct)
        a2[rt][ct] = __builtin_amdgcn_mfma_f32_16x16x32_bf16(
            af[rt], fw2[ct][ks], a2[rt][ct], 0, 0, 0);
  }
  __syncthreads();   // all zt reads done before overwrite

  // ---- o -> zt (reuse), then coalesced copy-out ----
#pragma unroll
  for (int rt = 0; rt < 4; ++rt)
#pragma unroll
    for (int ct = 0; ct < 2; ++ct) {
      int col = cb + (ct << 4) + lr;
      float bias = b2v[col];
#pragma unroll
      for (int r = 0; r < 4; ++r) {
        int row = (rt << 4) + (g << 2) + r;
        zt[ZIDX(row, col)] = f2b(fmaxf(a2[rt][ct][r] + bias, 0.f));
      }
    }
  __syncthreads();

  for (int i = tid; i < 1024; i += 256) {
    int mm = i >> 4, c0 = (i & 15) << 3;
    if (mm < nm) {
      uint4 v = *(const uint4*)&zt[ZIDX(mm, c0)];
      *(uint4*)&hout[(((size_t)(b * NN + t0 + mm)) << 7) + c0] = v;
    }
  }
}

// ---------------------------------------------------------------------------
// Heads (emb is bf16)
// ---------------------------------------------------------------------------
__global__ __launch_bounds__(256)
void heads_kernel(const u16* __restrict__ emb, const int* __restrict__ didx,
                  const int* __restrict__ nopp, const float* __restrict__ pol_w,
                  const float* __restrict__ pol_b, const float* __restrict__ val_w,
                  const float* __restrict__ val_b, float* __restrict__ out) {
  int gw = (blockIdx.x * blockDim.x + threadIdx.x) >> 6;
  int lane = threadIdx.x & 63;
  if (gw >= BB * KK) return;
  int b = gw / KK, k = gw - b * KK;
  int node = didx[b * KK + k];
  const u16* e = emb + (((size_t)(b * NN + node)) << 7);
  u32 v = *(const u32*)&e[lane << 1];
  float f0 = __uint_as_float(v << 16);
  float f1 = __uint_as_float(v & 0xffff0000u);
  float s = f0 * pol_w[lane << 1] + f1 * pol_w[(lane << 1) + 1];
#pragma unroll
  for (int off = 32; off; off >>= 1) s += __shfl_down(s, off);
  if (lane == 0) out[b * KK + k] = s + pol_b[0];
  if (k == nopp[0]) {
    float vv = f0 * val_w[lane << 1] + f1 * val_w[(lane << 1) + 1];
#pragma unroll
    for (int off = 32; off; off >>= 1) vv += __shfl_down(vv, off);
    if (lane == 0) out[BB * KK + b] = vv + val_b[0];
  }
}

// ---------------------------------------------------------------------------
extern "C" void kernel_launch(void* const* d_in, const int* in_sizes, int n_in,
                              void* d_out, int out_size, void* d_ws, size_t ws_size,
                              hipStream_t stream) {
  const float* x     = (const float*)d_in[0];
  const int*   edges = (const int*)d_in[1];
  const int*   didx  = (const int*)d_in[2];
  const int*   nopp  = (const int*)d_in[3];
  const float* w1f   = (const float*)d_in[4];
  const float* w1r   = (const float*)d_in[5];
  const float* w2    = (const float*)d_in[6];
  const float* b1    = (const float*)d_in[7];
  const float* b2    = (const float*)d_in[8];
  const float* pol_w = (const float*)d_in[9];
  const float* pol_b = (const float*)d_in[10];
  const float* val_w = (const float*)d_in[11];
  const float* val_b = (const float*)d_in[12];
  float* out = (float*)d_out;

  char* ws = (char*)d_ws;
  u16* hA = (u16*)ws;            ws += (size_t)BB * NN * CH * 2;   // 51.2 MB
  u16* hB = (u16*)ws;            ws += (size_t)BB * NN * CH * 2;   // 51.2 MB
  u16* img = (u16*)ws;           ws += (size_t)5 * CH * CH * 2;    // 160 KB
  int* offs = (int*)ws;          ws += (size_t)BB * (NN + 1) * 4;
  int* woff = (int*)ws;          ws += (size_t)BB * NN * 4;
  int* cnt  = (int*)ws;          ws += (size_t)BB * NN * 4;
  int* bsum = (int*)ws;          ws += (size_t)BB * SCAN_NB * 4;
  int* csr  = (int*)ws;          ws += (size_t)BB * EE * 4;

  prep_all<<<784, 256, 0, stream>>>(w1r, w2, img, cnt);
  csr_count<<<1250, 256, 0, stream>>>(edges, cnt);
  scan_local<<<dim3(SCAN_NB, BB), 256, 0, stream>>>(cnt, offs, bsum);
  scan_add<<<dim3(SCAN_NB, BB), 256, 0, stream>>>(offs, woff, bsum);
  csr_fill<<<1250, 256, 0, stream>>>(edges, woff, csr);

  gin_layer<true><<<TILES_TOTAL, 256, 0, stream>>>(
      x, hA, offs, csr, w1f, nullptr, img, b1, b2);
  gin_layer<false><<<TILES_TOTAL, 256, 0, stream>>>(
      hA, hB, offs, csr, nullptr, img + 1 * 16384, img + 2 * 16384,
      b1 + CH, b2 + CH);
  gin_layer<false><<<TILES_TOTAL, 256, 0, stream>>>(
      hB, hA, offs, csr, nullptr, img + 3 * 16384, img + 4 * 16384,
      b1 + 2 * CH, b2 + 2 * CH);

  heads_kernel<<<(BB * KK * 64 + 255) / 256, 256, 0, stream>>>(
      hA, didx, nopp, pol_w, pol_b, val_w, val_b, out);
}